// Round 3
// baseline (275.387 us; speedup 1.0000x reference)
//
#include <hip/hip_runtime.h>
#include <math.h>

// 1D grayscale dilation (max-plus conv), K=11, halo=5, fp32.
// out[i] = max_j ( x[i-5+j] + h[j] ),  h[j] = -(j-5)^2 / (4*scale)
//
// R1 lesson: thread-contiguous coarsening breaks per-instruction coalescing.
// R2 lesson: single-segment/thread lets the compiler minimize VGPRs (28!) by
//   serializing the loads -> ~2-3 loads in flight per wave -> latency-bound
//   at 3.3 TB/s with VALU and HBM both idle.
// R3: two block-strided segments per thread (q and q+T, both lane-contiguous),
//   ALL 10 VMEM issued before dependent compute (A-compute overlaps B-loads
//   via fine-grained vmcnt). Read redundancy 5x -> 3.5x (3 float4 + 2 dword
//   halo loads per segment). Symmetric-h max-plus: 15 VALU/output.

#define HALF 5

__global__ __launch_bounds__(256) void dilate1d_kernel(
    const float*  __restrict__ x,
    const float*  __restrict__ scale_p,
    float4*       __restrict__ out4,
    int n4,   // number of float4 elements in x / out
    int T)    // segment stride in float4 units (= ceil(n4/2))
{
    const float s = scale_p[0];
    // hp[d] = -d^2/(4s), d=0..5 ; h[j] = hp[|j-5|]
    float hp1 = -1.0f  / (4.0f * s);
    float hp2 = -4.0f  / (4.0f * s);
    float hp3 = -9.0f  / (4.0f * s);
    float hp4 = -16.0f / (4.0f * s);
    float hp5 = -25.0f / (4.0f * s);

    const float NEG = -INFINITY;
    const float4 NEG4 = make_float4(NEG, NEG, NEG, NEG);
    const float4* x4 = (const float4*)x;

    const int qA = blockIdx.x * blockDim.x + threadIdx.x;  // < T by grid sizing
    const int qB = qA + T;
    const bool hasB = (qB < n4);

    // ---- issue ALL loads up front (10 VMEM) ----
    // segment A
    float4 amid = x4[qA];
    float4 alo  = (qA >= 1)      ? x4[qA - 1] : NEG4;
    float4 ahi  = (qA + 1 < n4)  ? x4[qA + 1] : NEG4;
    float  axl  = (qA >= 2)      ? x[4 * qA - 5] : NEG;
    float  axr  = (qA + 2 < n4)  ? x[4 * qA + 8] : NEG;
    // segment B (predicated; OOB lanes produce garbage we never store)
    float4 bmid = hasB               ? x4[qB]     : NEG4;
    float4 blo  = (qB >= 1 && hasB)  ? x4[qB - 1] : NEG4;
    float4 bhi  = (qB + 1 < n4)      ? x4[qB + 1] : NEG4;
    float  bxl  = (qB >= 2 && hasB)  ? x[4 * qB - 5] : NEG;
    float  bxr  = (qB + 2 < n4)      ? x[4 * qB + 8] : NEG;

    float w[14];
    float hparr[6];
    hparr[1] = hp1; hparr[2] = hp2; hparr[3] = hp3; hparr[4] = hp4; hparr[5] = hp5;

    // ---- segment A compute ----
    w[0] = axl;
    w[1] = alo.x;  w[2] = alo.y;  w[3] = alo.z;  w[4] = alo.w;
    w[5] = amid.x; w[6] = amid.y; w[7] = amid.z; w[8] = amid.w;
    w[9] = ahi.x;  w[10] = ahi.y; w[11] = ahi.z; w[12] = ahi.w;
    w[13] = axr;

    float4 oA;
    {
        float* op = &oA.x;
#pragma unroll
        for (int i = 0; i < 4; ++i) {
            int c = HALF + i;
            float m = w[c];  // hp[0] == 0
#pragma unroll
            for (int d = 1; d <= HALF; ++d) {
                m = fmaxf(m, hparr[d] + fmaxf(w[c - d], w[c + d]));
            }
            op[i] = m;
        }
    }
    out4[qA] = oA;

    // ---- segment B compute ----
    w[0] = bxl;
    w[1] = blo.x;  w[2] = blo.y;  w[3] = blo.z;  w[4] = blo.w;
    w[5] = bmid.x; w[6] = bmid.y; w[7] = bmid.z; w[8] = bmid.w;
    w[9] = bhi.x;  w[10] = bhi.y; w[11] = bhi.z; w[12] = bhi.w;
    w[13] = bxr;

    float4 oB;
    {
        float* op = &oB.x;
#pragma unroll
        for (int i = 0; i < 4; ++i) {
            int c = HALF + i;
            float m = w[c];
#pragma unroll
            for (int d = 1; d <= HALF; ++d) {
                m = fmaxf(m, hparr[d] + fmaxf(w[c - d], w[c + d]));
            }
            op[i] = m;
        }
    }
    if (hasB) out4[qB] = oB;
}

extern "C" void kernel_launch(void* const* d_in, const int* in_sizes, int n_in,
                              void* d_out, int out_size, void* d_ws, size_t ws_size,
                              hipStream_t stream) {
    const float* x       = (const float*)d_in[0];
    const float* scale_p = (const float*)d_in[1];
    float*       out     = (float*)d_out;

    int n  = in_sizes[0];
    int n4 = n / 4;              // n = 2^25 -> n4 = 2^23
    int T  = (n4 + 1) / 2;       // segment stride; thread t handles t and t+T

    int block = 256;
    int grid  = (T + block - 1) / block;

    dilate1d_kernel<<<grid, block, 0, stream>>>(
        x, scale_p, (float4*)out, n4, T);
}

// Round 4
// 229.671 us; speedup vs baseline: 1.1990x; 1.1990x over previous
//
#include <hip/hip_runtime.h>
#include <math.h>

// 1D grayscale dilation (max-plus conv), K=11, halo=5, fp32.
// out[i] = max_j ( x[i-5+j] + h[j] ),  h[j] = -(j-5)^2 / (4*scale)
//
// R1 lesson: thread-contiguous coarsening breaks per-instruction coalescing.
// R2/R3 lesson: any structure where reused inputs live in VGPRs gets
//   serialized by the compiler's register minimizer (VGPR=28/20!) -> ~1-2
//   loads in flight per wave -> latency-bound at 2-3 TB/s, VALU and HBM idle.
// R4: LDS-staged tile. Each block stages 1024 quads + 2-quad halo into LDS
//   with one independent float4 load per thread per step (loads have no reg
//   consumer except ds_write -> compiler clusters them, vmcnt(3..0) stagger).
//   Global read redundancy 5x -> 1.0x. Compute reads 5x ds_read_b128/quad
//   (consecutive 16B lane addrs, conflict-free). Wave-uniform edge branch.

#define BLOCK   256
#define QPT     4                      // output quads per thread
#define TILE_Q  (BLOCK * QPT)          // 1024 quads per block
#define HALO_Q  2                      // staged halo quads each side
#define STAGE_Q (TILE_Q + 2 * HALO_Q)  // 1028 quads = 16448 B LDS

__global__ __launch_bounds__(BLOCK) void dilate1d_kernel(
    const float4* __restrict__ x4,
    const float*  __restrict__ scale_p,
    float4*       __restrict__ out4,
    int n4)   // number of float4 elements in x / out
{
    __shared__ float4 smem[STAGE_Q];

    const float NEG  = -INFINITY;
    const float4 NEG4 = make_float4(NEG, NEG, NEG, NEG);

    const int Q0 = blockIdx.x * TILE_Q;          // first output quad of tile
    const int g0 = Q0 - HALO_Q;                  // first staged quad (global)

    // ---- stage tile + halo into LDS ----
    const bool interior = (g0 >= 0) && (g0 + STAGE_Q <= n4);
    if (interior) {
#pragma unroll
        for (int t = 0; t < QPT; ++t) {
            int idx = threadIdx.x + t * BLOCK;
            smem[idx] = x4[g0 + idx];
        }
        if (threadIdx.x < 2 * HALO_Q) {
            int idx = TILE_Q + threadIdx.x;      // 1024..1027
            smem[idx] = x4[g0 + idx];
        }
    } else {
        // only blocks 0 and gridDim-1 take this path
#pragma unroll
        for (int t = 0; t <= QPT; ++t) {
            int idx = threadIdx.x + t * BLOCK;
            if (idx < STAGE_Q) {
                int g = g0 + idx;
                smem[idx] = (g >= 0 && g < n4) ? x4[g] : NEG4;
            }
        }
    }
    __syncthreads();

    // ---- structuring element: hp[d] = -d^2/(4s), h[j] = hp[|j-5|] ----
    const float r4s = 1.0f / (4.0f * scale_p[0]);   // one div per thread
    float hparr[6];
    hparr[0] = 0.0f;
    hparr[1] = -1.0f  * r4s;
    hparr[2] = -4.0f  * r4s;
    hparr[3] = -9.0f  * r4s;
    hparr[4] = -16.0f * r4s;
    hparr[5] = -25.0f * r4s;

    // ---- compute: block-strided quads (lane-contiguous LDS reads/stores) ----
#pragma unroll
    for (int t = 0; t < QPT; ++t) {
        int idx = threadIdx.x + t * BLOCK;       // tile-local quad
        int q   = Q0 + idx;                      // global output quad
        if (q >= n4) break;

        // w[k] = x[4*q + k - 8], k = 0..19  (5 consecutive ds_read_b128)
        float w[20];
#pragma unroll
        for (int r = 0; r < 5; ++r) {
            float4 v = smem[idx + r];            // staged quad (idx+HALO_Q)-2+r
            w[4 * r + 0] = v.x;
            w[4 * r + 1] = v.y;
            w[4 * r + 2] = v.z;
            w[4 * r + 3] = v.w;
        }

        float4 o;
        float* op = &o.x;
#pragma unroll
        for (int i = 0; i < 4; ++i) {
            int c = 8 + i;                       // center of window in w
            float m = w[c];                      // hp[0] == 0
#pragma unroll
            for (int d = 1; d <= 5; ++d) {
                m = fmaxf(m, hparr[d] + fmaxf(w[c - d], w[c + d]));
            }
            op[i] = m;
        }
        out4[q] = o;
    }
}

extern "C" void kernel_launch(void* const* d_in, const int* in_sizes, int n_in,
                              void* d_out, int out_size, void* d_ws, size_t ws_size,
                              hipStream_t stream) {
    const float* x       = (const float*)d_in[0];
    const float* scale_p = (const float*)d_in[1];
    float*       out     = (float*)d_out;

    int n  = in_sizes[0];
    int n4 = n / 4;                              // n = 2^25 -> n4 = 2^23

    int grid = (n4 + TILE_Q - 1) / TILE_Q;       // 8192 blocks

    dilate1d_kernel<<<grid, BLOCK, 0, stream>>>(
        (const float4*)x, scale_p, (float4*)out, n4);
}